// Round 2
// baseline (273.631 us; speedup 1.0000x reference)
//
#include <hip/hip_runtime.h>
#include <math.h>

#define NB 4
#define NL 256
#define ND 512
#define NH 8
#define NR 64
#define NDK 64

typedef float f32x4 __attribute__((ext_vector_type(4)));

// ---------------------------------------------------------------------------
// Kernel 1: QKV projection.  q/k/v = x @ W^T + b, stored as [B,H,L,DK].
// 32x64 output tiles (grid 32x8x3 = 768 blocks -> 3/CU), 2x4 micro-tile.
// ---------------------------------------------------------------------------
__global__ __launch_bounds__(256)
void qkv_proj_kernel(const float* __restrict__ Xq, const float* __restrict__ Xk,
                     const float* __restrict__ Xv,
                     const float* __restrict__ Wq, const float* __restrict__ bq,
                     const float* __restrict__ Wk, const float* __restrict__ bk,
                     const float* __restrict__ Wv, const float* __restrict__ bv,
                     float* __restrict__ Oq, float* __restrict__ Ok,
                     float* __restrict__ Ov)
{
    const int z = blockIdx.z;
    const float* __restrict__ X    = (z == 0) ? Xq : ((z == 1) ? Xk : Xv);
    const float* __restrict__ W    = (z == 0) ? Wq : ((z == 1) ? Wk : Wv);
    const float* __restrict__ bias = (z == 0) ? bq : ((z == 1) ? bk : bv);
    float* __restrict__ Out        = (z == 0) ? Oq : ((z == 1) ? Ok : Ov);

    __shared__ float As[32][17];
    __shared__ float Bs[64][17];

    const int t  = threadIdx.x;
    const int ty = t >> 4;            // 0..15
    const int tx = t & 15;            // 0..15

    const int row0 = blockIdx.x * 32; // over M = B*L = 1024
    const int h    = blockIdx.y;      // head == 64-col tile
    const int col0 = h * 64;

    float acc[2][4] = {{0.f,0.f,0.f,0.f},{0.f,0.f,0.f,0.f}};

    for (int kt = 0; kt < ND; kt += 16) {
        if (t < 128) {
            int lr = t >> 2, lk = (t & 3) << 2;
            *(f32x4*)&As[lr][lk] = *(const f32x4*)&X[(size_t)(row0 + lr) * ND + kt + lk];
        }
        {
            int lr = t >> 2, lk = (t & 3) << 2;
            *(f32x4*)&Bs[lr][lk] = *(const f32x4*)&W[(size_t)(col0 + lr) * ND + kt + lk];
        }
        __syncthreads();
        #pragma unroll
        for (int kk = 0; kk < 16; ++kk) {
            float a0 = As[ty*2 + 0][kk];
            float a1 = As[ty*2 + 1][kk];
            #pragma unroll
            for (int j = 0; j < 4; ++j) {
                float bb = Bs[tx*4 + j][kk];
                acc[0][j] += a0 * bb;
                acc[1][j] += a1 * bb;
            }
        }
        __syncthreads();
    }

    float b0 = bias[col0 + tx*4 + 0];
    float b1 = bias[col0 + tx*4 + 1];
    float b2 = bias[col0 + tx*4 + 2];
    float b3 = bias[col0 + tx*4 + 3];
    #pragma unroll
    for (int i = 0; i < 2; ++i) {
        int r  = row0 + ty*2 + i;
        int bb = r >> 8;
        int ll = r & 255;
        f32x4 o;
        o.x = acc[i][0] + b0; o.y = acc[i][1] + b1;
        o.z = acc[i][2] + b2; o.w = acc[i][3] + b3;
        *(f32x4*)&Out[(((size_t)(bb*NH + h) * NL) + ll) * NDK + tx*4] = o;
    }
}

// ---------------------------------------------------------------------------
// Kernel 2: p2c = k . rel_q^T   -> [B,H,L,R]  (c2p is computed in the fused
// kernel).  64x64 tile per block, 4x4 micro-tile, K=64.
// ---------------------------------------------------------------------------
__global__ __launch_bounds__(256)
void p2c_kernel(const float* __restrict__ K, const float* __restrict__ RelQ,
                float* __restrict__ P2C)
{
    const int bh = blockIdx.y;
    const int h  = bh & 7;
    const int l0 = blockIdx.x * 64;

    const float* __restrict__ A  = K + (size_t)bh * NL * NDK + (size_t)l0 * NDK;
    const float* __restrict__ Bm = RelQ + (size_t)h * NR * NDK;
    float* __restrict__ C        = P2C + (size_t)bh * NL * NR + (size_t)l0 * NR;

    __shared__ float As[64][17];
    __shared__ float Bs[64][17];

    const int t  = threadIdx.x;
    const int lr = t >> 2;
    const int lk = (t & 3) << 2;
    const int ty = t >> 4;
    const int tx = t & 15;

    float acc[4][4] = {{0.f,0.f,0.f,0.f},{0.f,0.f,0.f,0.f},
                       {0.f,0.f,0.f,0.f},{0.f,0.f,0.f,0.f}};

    for (int kt = 0; kt < NDK; kt += 16) {
        *(f32x4*)&As[lr][lk] = *(const f32x4*)&A[(size_t)lr * NDK + kt + lk];
        *(f32x4*)&Bs[lr][lk] = *(const f32x4*)&Bm[(size_t)lr * NDK + kt + lk];
        __syncthreads();
        #pragma unroll
        for (int kk = 0; kk < 16; ++kk) {
            float a[4], b[4];
            #pragma unroll
            for (int i = 0; i < 4; ++i) a[i] = As[ty*4 + i][kk];
            #pragma unroll
            for (int j = 0; j < 4; ++j) b[j] = Bs[tx*4 + j][kk];
            #pragma unroll
            for (int i = 0; i < 4; ++i)
                #pragma unroll
                for (int j = 0; j < 4; ++j) acc[i][j] += a[i] * b[j];
        }
        __syncthreads();
    }

    #pragma unroll
    for (int i = 0; i < 4; ++i) {
        f32x4 o;
        o.x = acc[i][0]; o.y = acc[i][1]; o.z = acc[i][2]; o.w = acc[i][3];
        *(f32x4*)&C[(size_t)(ty*4 + i) * NR + tx*4] = o;
    }
}

// ---------------------------------------------------------------------------
// Kernel 3 (FUSED): per (b,l) block -> c2p row, QK^T row, gathers, mask,
// softmax (in-register), then ctx row streaming rel_v (nontemporal) fused
// with p@V.  XCD-bijective swizzle: XCD x serves b = x>>1 so K[b]+V[b]+p2c[b]
// (3 MB) stay resident in that XCD's 4 MB L2.
// ---------------------------------------------------------------------------
__global__ __launch_bounds__(256)
void fused_attn_kernel(const float* __restrict__ Q, const float* __restrict__ Kp,
                       const float* __restrict__ Vp,
                       const float* __restrict__ RelK, const float* __restrict__ P2C,
                       const int* __restrict__ RelPos, const void* __restrict__ MaskP,
                       const float* __restrict__ RV, float* __restrict__ CTX)
{
    // ---- XCD swizzle: bid%8 = XCD (perf heuristic only; bijective) ----
    const int bid = blockIdx.x;
    const int x   = bid & 7;
    const int idx = bid >> 3;            // 0..127
    const int b   = x >> 1;
    const int l   = (x & 1) * 128 + idx;
    const int bl  = b * NL + l;
    const int t   = threadIdx.x;

    __shared__ float qrow[8][64];    // 2 KB
    __shared__ float c2p[8][64];     // 2 KB
    __shared__ float sc[8][256];     // 8 KB (scores, then p)
    __shared__ f32x4 redv[128];      // 2 KB
    __shared__ float rscr[8][8];     // reduction scratch

    // ---- detect mask buffer layout (bool-u8 / f32 / i32), deterministic ----
    const unsigned char* mu = (const unsigned char*)MaskP;
    int loc1  = mu[t*4 + 1];
    int loc23 = mu[t*4 + 2] | mu[t*4 + 3];
    int any1  = __syncthreads_or(loc1);
    int any23 = __syncthreads_or(loc23);
    const int mlayout = any1 ? 0 : (any23 ? 1 : 2);  // 0=u8, 1=f32, 2=i32

    // ---- stage q row [8][64] ----
    if (t < 128) {
        int h = t >> 4, d4 = (t & 15) << 2;
        *(f32x4*)&qrow[h][d4] =
            *(const f32x4*)&Q[(((size_t)(b*NH + h)) * NL + l) * NDK + d4];
    }
    __syncthreads();

    // ---- c2p[h][r] = q[h,:] . rel_k[h,r,:]  (2 outputs per thread) ----
    #pragma unroll
    for (int rep = 0; rep < 2; ++rep) {
        int id = t + rep * 256;
        int h  = id >> 6, r = id & 63;
        float s = 0.f;
        #pragma unroll
        for (int d4 = 0; d4 < 16; ++d4) {
            f32x4 qq = *(const f32x4*)&qrow[h][d4 << 2];
            f32x4 rk = *(const f32x4*)&RelK[(((size_t)h) * NR + r) * NDK + (d4 << 2)];
            s += qq.x*rk.x + qq.y*rk.y + qq.z*rk.z + qq.w*rk.w;
        }
        c2p[h][r] = s;
    }

    // ---- QK^T: quad-split (4 lanes share one k-row -> 64B-coalesced) ----
    {
        const int m0 = t >> 2;     // 0..63
        const int dq = t & 3;      // d-quarter
        #pragma unroll 1
        for (int h = 0; h < 8; ++h) {
            const size_t kbase = (((size_t)(b*NH + h)) * NL) * NDK;
            #pragma unroll
            for (int pass = 0; pass < 4; ++pass) {
                int m = m0 + pass * 64;
                const f32x4* kr = (const f32x4*)&Kp[kbase + (size_t)m * NDK + dq * 16];
                float s = 0.f;
                #pragma unroll
                for (int q4 = 0; q4 < 4; ++q4) {
                    f32x4 qq = *(const f32x4*)&qrow[h][dq*16 + q4*4];
                    f32x4 kk = kr[q4];
                    s += qq.x*kk.x + qq.y*kk.y + qq.z*kk.z + qq.w*kk.w;
                }
                s += __shfl_xor(s, 1);
                s += __shfl_xor(s, 2);
                if (dq == 0) sc[h][m] = s;
            }
        }
    }
    __syncthreads();

    // ---- gathers + scale + mask (thread t owns column m = t) ----
    const int rpv = RelPos[(((size_t)b) * NL + l) * NL + t];
    float mval;
    if (mlayout == 0)      mval = (float)mu[b * NL + t];
    else if (mlayout == 1) mval = ((const float*)MaskP)[b * NL + t];
    else                   mval = (float)((const int*)MaskP)[b * NL + t];
    const bool masked = (mval != 0.0f);

    float sv[8];
    #pragma unroll
    for (int h = 0; h < 8; ++h) {
        float s = sc[h][t] + c2p[h][rpv]
                + P2C[((((size_t)(b*NH + h)) * NL) + t) * NR + rpv];
        s *= (1.0f / 24.0f);   // 1 / (3 * sqrt(64))
        sv[h] = masked ? -1e9f : s;
    }

    // ---- softmax over m (256 threads): wave butterfly + 4-wave combine ----
    const int w    = t >> 6;
    const int lane = t & 63;
    #pragma unroll
    for (int h = 0; h < 8; ++h) {
        float m = sv[h];
        #pragma unroll
        for (int off = 32; off >= 1; off >>= 1) m = fmaxf(m, __shfl_xor(m, off));
        if (lane == 0) rscr[h][w] = m;
    }
    __syncthreads();
    #pragma unroll
    for (int h = 0; h < 8; ++h) {
        float gm = fmaxf(fmaxf(rscr[h][0], rscr[h][1]), fmaxf(rscr[h][2], rscr[h][3]));
        sv[h] = __expf(sv[h] - gm);
    }
    #pragma unroll
    for (int h = 0; h < 8; ++h) {
        float s = sv[h];
        #pragma unroll
        for (int off = 32; off >= 1; off >>= 1) s += __shfl_xor(s, off);
        if (lane == 0) rscr[h][4 + w] = s;
    }
    __syncthreads();
    #pragma unroll
    for (int h = 0; h < 8; ++h) {
        float dsum = rscr[h][4] + rscr[h][5] + rscr[h][6] + rscr[h][7];
        sc[h][t] = sv[h] / dsum;     // p
    }
    __syncthreads();

    // ---- ctx: stream rel_v slice (nontemporal) fused with p@V ----
    const int c    = t & 127;    // float4-column 0..127 (head = c>>4)
    const int half = t >> 7;     // m parity
    const int hc   = c >> 4;
    const int dk4  = c & 15;

    const f32x4* rv4 = (const f32x4*)RV + (size_t)bl * NL * 128 + c;
    const f32x4* vv4 = (const f32x4*)Vp + ((size_t)(b*NH + hc) * NL) * 16 + dk4;

    f32x4 acc = {0.f, 0.f, 0.f, 0.f};
    #pragma unroll 4
    for (int m = half; m < NL; m += 2) {
        float wgt = sc[hc][m];
        f32x4 rv = __builtin_nontemporal_load(rv4 + (size_t)m * 128);
        f32x4 vv = vv4[(size_t)m * 16];
        acc += wgt * (rv + vv);
    }

    if (half) redv[c] = acc;
    __syncthreads();
    if (!half) {
        acc += redv[c];
        *(f32x4*)&CTX[(size_t)bl * ND + c*4] = acc;
    }
}

// ---------------------------------------------------------------------------
// Kernel 4: out = ctx @ Wo^T + bo.  32x64 tiles (256 blocks -> 1/CU).
// ---------------------------------------------------------------------------
__global__ __launch_bounds__(256)
void out_proj_kernel(const float* __restrict__ A, const float* __restrict__ W,
                     const float* __restrict__ bias, float* __restrict__ C)
{
    __shared__ float As[32][17];
    __shared__ float Bs[64][17];

    const int t  = threadIdx.x;
    const int ty = t >> 4;
    const int tx = t & 15;

    const int row0 = blockIdx.x * 32;
    const int col0 = blockIdx.y * 64;

    float acc[2][4] = {{0.f,0.f,0.f,0.f},{0.f,0.f,0.f,0.f}};

    for (int kt = 0; kt < ND; kt += 16) {
        if (t < 128) {
            int lr = t >> 2, lk = (t & 3) << 2;
            *(f32x4*)&As[lr][lk] = *(const f32x4*)&A[(size_t)(row0 + lr) * ND + kt + lk];
        }
        {
            int lr = t >> 2, lk = (t & 3) << 2;
            *(f32x4*)&Bs[lr][lk] = *(const f32x4*)&W[(size_t)(col0 + lr) * ND + kt + lk];
        }
        __syncthreads();
        #pragma unroll
        for (int kk = 0; kk < 16; ++kk) {
            float a0 = As[ty*2 + 0][kk];
            float a1 = As[ty*2 + 1][kk];
            #pragma unroll
            for (int j = 0; j < 4; ++j) {
                float bb = Bs[tx*4 + j][kk];
                acc[0][j] += a0 * bb;
                acc[1][j] += a1 * bb;
            }
        }
        __syncthreads();
    }

    float b0 = bias[col0 + tx*4 + 0];
    float b1 = bias[col0 + tx*4 + 1];
    float b2 = bias[col0 + tx*4 + 2];
    float b3 = bias[col0 + tx*4 + 3];
    #pragma unroll
    for (int i = 0; i < 2; ++i) {
        int r = row0 + ty*2 + i;
        f32x4 o;
        o.x = acc[i][0] + b0; o.y = acc[i][1] + b1;
        o.z = acc[i][2] + b2; o.w = acc[i][3] + b3;
        *(f32x4*)&C[(size_t)r * ND + col0 + tx*4] = o;
    }
}

// ---------------------------------------------------------------------------
extern "C" void kernel_launch(void* const* d_in, const int* in_sizes, int n_in,
                              void* d_out, int out_size, void* d_ws, size_t ws_size,
                              hipStream_t stream)
{
    const float* query   = (const float*)d_in[0];
    const float* key     = (const float*)d_in[1];
    const float* value   = (const float*)d_in[2];
    const void*  mask    = d_in[3];
    const int*   rel_pos = (const int*)d_in[4];
    const float* rel_q   = (const float*)d_in[5];
    const float* rel_k   = (const float*)d_in[6];
    const float* rel_v   = (const float*)d_in[7];
    const float* Wq = (const float*)d_in[8];
    const float* bq = (const float*)d_in[9];
    const float* Wk = (const float*)d_in[10];
    const float* bk = (const float*)d_in[11];
    const float* Wv = (const float*)d_in[12];
    const float* bv = (const float*)d_in[13];
    const float* Wo = (const float*)d_in[14];
    const float* bo = (const float*)d_in[15];

    float* ws   = (float*)d_ws;
    float* q_ws = ws;                     // B*H*L*DK = 524288
    float* k_ws = q_ws + 524288;
    float* v_ws = k_ws + 524288;
    float* p2c  = v_ws + 524288;          // B*H*L*R = 524288
    float* ctx  = p2c + 524288;           // B*L*D   = 524288

    qkv_proj_kernel<<<dim3(32, 8, 3), 256, 0, stream>>>(
        query, key, value, Wq, bq, Wk, bk, Wv, bv, q_ws, k_ws, v_ws);

    p2c_kernel<<<dim3(4, 32), 256, 0, stream>>>(k_ws, rel_q, p2c);

    fused_attn_kernel<<<dim3(1024), 256, 0, stream>>>(
        q_ws, k_ws, v_ws, rel_k, p2c, rel_pos, mask, rel_v, ctx);

    out_proj_kernel<<<dim3(32, 8), 256, 0, stream>>>(ctx, Wo, bo, (float*)d_out);
}

// Round 3
// 205.116 us; speedup vs baseline: 1.3340x; 1.3340x over previous
//
#include <hip/hip_runtime.h>
#include <math.h>

#define NB 4
#define NL 256
#define ND 512
#define NH 8
#define NR 64
#define NDK 64

typedef float f32x4 __attribute__((ext_vector_type(4)));

// ---------------------------------------------------------------------------
// Kernel 0: W-prep.
//  z=0: W3[h*64+r][e] = sum_d rel_k[h,r,d] * Wq[h*64+d][e]   (for c2p)
//  z=1: W2[h*64+r][e] = sum_d rel_q[h,r,d] * Wk[h*64+d][e]   (for p2c)
//  z=2 (blocks 0,1 only): b3[hr] = rel_k[h,r,:].bq_head ; b2 from rel_q,bk
// ---------------------------------------------------------------------------
__global__ __launch_bounds__(256)
void wprep_kernel(const float* __restrict__ Wq, const float* __restrict__ bq,
                  const float* __restrict__ Wk, const float* __restrict__ bk,
                  const float* __restrict__ RelK, const float* __restrict__ RelQ,
                  float* __restrict__ W3, float* __restrict__ b3,
                  float* __restrict__ W2, float* __restrict__ b2)
{
    const int z = blockIdx.y;
    const int t = threadIdx.x;

    if (z == 2) {
        if (blockIdx.x >= 2) return;
        const float* rel  = blockIdx.x ? RelQ : RelK;
        const float* bias = blockIdx.x ? bk : bq;
        float* out        = blockIdx.x ? b2 : b3;
        for (int hr = t; hr < 512; hr += 256) {
            int h = hr >> 6, r = hr & 63;
            float s = 0.f;
            #pragma unroll 8
            for (int d = 0; d < 64; ++d)
                s += rel[((size_t)h * NR + r) * NDK + d] * bias[h * 64 + d];
            out[hr] = s;
        }
        return;
    }

    const float* rel = z ? RelQ : RelK;   // [8][64][64]
    const float* W   = z ? Wk : Wq;       // [512][512]
    float* Wout      = z ? W2 : W3;

    const int h  = blockIdx.x >> 3;
    const int e0 = (blockIdx.x & 7) * 64;

    __shared__ float At[64][68];   // At[d][r]
    __shared__ float Bs[64][68];   // Bs[d][e]

    const int ty = t >> 4, tx = t & 15;

    #pragma unroll
    for (int pass = 0; pass < 4; ++pass) {
        {   // A = rel[h]  [64 r][64 d] -> At[d][r]
            int lr = t >> 2, lk = (t & 3) << 2;
            f32x4 a = *(const f32x4*)&rel[((size_t)h * NR + lr) * NDK + pass * 16 + lk];
            At[pass*16 + lk + 0][lr] = a.x; At[pass*16 + lk + 1][lr] = a.y;
            At[pass*16 + lk + 2][lr] = a.z; At[pass*16 + lk + 3][lr] = a.w;
        }
        {   // B rows d -> Bs[d][e]
            int dr = t >> 4, ec = (t & 15) << 2;
            *(f32x4*)&Bs[pass*16 + dr][ec] =
                *(const f32x4*)&W[(size_t)(h*64 + pass*16 + dr) * ND + e0 + ec];
        }
    }
    __syncthreads();

    float acc[4][4] = {{0.f,0.f,0.f,0.f},{0.f,0.f,0.f,0.f},
                       {0.f,0.f,0.f,0.f},{0.f,0.f,0.f,0.f}};
    #pragma unroll 16
    for (int kk = 0; kk < 64; ++kk) {
        f32x4 a4 = *(const f32x4*)&At[kk][ty*4];
        f32x4 b4 = *(const f32x4*)&Bs[kk][tx*4];
        #pragma unroll
        for (int i = 0; i < 4; ++i) {
            acc[i][0] += a4[i]*b4.x; acc[i][1] += a4[i]*b4.y;
            acc[i][2] += a4[i]*b4.z; acc[i][3] += a4[i]*b4.w;
        }
    }

    #pragma unroll
    for (int i = 0; i < 4; ++i) {
        f32x4 o; o.x = acc[i][0]; o.y = acc[i][1]; o.z = acc[i][2]; o.w = acc[i][3];
        *(f32x4*)&Wout[(size_t)(h*64 + ty*4 + i) * ND + e0 + tx*4] = o;
    }
}

// ---------------------------------------------------------------------------
// Kernel 1: batched projection GEMM.  Out = X @ W^T + bias for 5 slices:
//  z=0 q, z=1 k, z=2 v, z=3 c2p (X=query,W=W3), z=4 p2c (X=key,W=W2).
// All outputs stored [B,H,L,64].  32x64 tiles, grid (32,8,5)=1280 = 5/CU.
// Transposed LDS: fragments read as ds_read_b64/b128.
// ---------------------------------------------------------------------------
__global__ __launch_bounds__(256)
void gemm5_kernel(const float* __restrict__ query, const float* __restrict__ key,
                  const float* __restrict__ value,
                  const float* __restrict__ Wq, const float* __restrict__ bq,
                  const float* __restrict__ Wk, const float* __restrict__ bk,
                  const float* __restrict__ Wv, const float* __restrict__ bv,
                  const float* __restrict__ W3, const float* __restrict__ b3,
                  const float* __restrict__ W2, const float* __restrict__ b2,
                  float* __restrict__ q_ws, float* __restrict__ k_ws,
                  float* __restrict__ v_ws, float* __restrict__ c2p,
                  float* __restrict__ p2c)
{
    const int z = blockIdx.z;
    const float* __restrict__ X    = (z==0 || z==3) ? query : ((z==1 || z==4) ? key : value);
    const float* __restrict__ W    = (z==0)?Wq:(z==1)?Wk:(z==2)?Wv:(z==3)?W3:W2;
    const float* __restrict__ bias = (z==0)?bq:(z==1)?bk:(z==2)?bv:(z==3)?b3:b2;
    float* __restrict__ Out        = (z==0)?q_ws:(z==1)?k_ws:(z==2)?v_ws:(z==3)?c2p:p2c;

    __shared__ float Ast[16][36];  // Ast[kk][row]
    __shared__ float Bst[16][68];  // Bst[kk][col]

    const int t  = threadIdx.x;
    const int ty = t >> 4;          // 0..15 -> 2 rows each
    const int tx = t & 15;          // 0..15 -> 4 cols each

    const int row0 = blockIdx.x * 32;
    const int h    = blockIdx.y;
    const int col0 = h * 64;

    float acc[2][4] = {{0.f,0.f,0.f,0.f},{0.f,0.f,0.f,0.f}};

    for (int kt = 0; kt < ND; kt += 16) {
        if (t < 128) {
            int lr = t >> 2, lk = (t & 3) << 2;
            f32x4 a = *(const f32x4*)&X[(size_t)(row0 + lr) * ND + kt + lk];
            Ast[lk+0][lr] = a.x; Ast[lk+1][lr] = a.y;
            Ast[lk+2][lr] = a.z; Ast[lk+3][lr] = a.w;
        }
        {
            int lr = t >> 2, lk = (t & 3) << 2;
            f32x4 b = *(const f32x4*)&W[(size_t)(col0 + lr) * ND + kt + lk];
            Bst[lk+0][lr] = b.x; Bst[lk+1][lr] = b.y;
            Bst[lk+2][lr] = b.z; Bst[lk+3][lr] = b.w;
        }
        __syncthreads();
        #pragma unroll
        for (int kk = 0; kk < 16; ++kk) {
            float2 a2 = *(const float2*)&Ast[kk][ty*2];
            f32x4  b4 = *(const f32x4*)&Bst[kk][tx*4];
            acc[0][0] += a2.x*b4.x; acc[0][1] += a2.x*b4.y;
            acc[0][2] += a2.x*b4.z; acc[0][3] += a2.x*b4.w;
            acc[1][0] += a2.y*b4.x; acc[1][1] += a2.y*b4.y;
            acc[1][2] += a2.y*b4.z; acc[1][3] += a2.y*b4.w;
        }
        __syncthreads();
    }

    f32x4 bb = *(const f32x4*)&bias[col0 + tx*4];
    #pragma unroll
    for (int i = 0; i < 2; ++i) {
        int r  = row0 + ty*2 + i;
        int bI = r >> 8;
        int lI = r & 255;
        f32x4 o;
        o.x = acc[i][0] + bb.x; o.y = acc[i][1] + bb.y;
        o.z = acc[i][2] + bb.z; o.w = acc[i][3] + bb.w;
        *(f32x4*)&Out[(((size_t)(bI*NH + h) * NL) + lI) * 64 + tx*4] = o;
    }
}

// ---------------------------------------------------------------------------
// Kernel 2: scores + gathers + scale + mask + softmax -> p [B,H,L,L]
// Block: (16-row l-tile, bh).  Vectorized f32x4 LDS dots.
// ---------------------------------------------------------------------------
__global__ __launch_bounds__(256)
void scores_softmax_kernel(const float* __restrict__ Q, const float* __restrict__ K,
                           const float* __restrict__ C2P, const float* __restrict__ P2C,
                           const int* __restrict__ RelPos, const void* __restrict__ MaskP,
                           float* __restrict__ Pout)
{
    const int bh = blockIdx.y;
    const int b  = bh >> 3;
    const int l0 = blockIdx.x * 16;
    const int t  = threadIdx.x;
    const int i  = t >> 4;
    const int j  = t & 15;

    __shared__ float qs[16][68];
    __shared__ float cs[16][64];
    __shared__ float ks[16][68];
    __shared__ float ps[16][64];
    __shared__ float sc[16][256];
    __shared__ int   rp[16][16];

    // ---- detect mask buffer layout (bool-u8 / f32 / i32), deterministic ----
    const unsigned char* mu = (const unsigned char*)MaskP;
    int loc1  = mu[t*4 + 1];
    int loc23 = mu[t*4 + 2] | mu[t*4 + 3];
    int any1  = __syncthreads_or(loc1);
    int any23 = __syncthreads_or(loc23);
    const int mlayout = any1 ? 0 : (any23 ? 1 : 2);  // 0=u8, 1=f32, 2=i32

    // ---- stage q rows + c2p rows (row i, f32x4 at col j*4) ----
    {
        f32x4 a = *(const f32x4*)&Q[((size_t)bh * NL + l0 + i) * NDK + j*4];
        *(f32x4*)&qs[i][j*4] = a;
        f32x4 c = *(const f32x4*)&C2P[((size_t)bh * NL + l0 + i) * NR + j*4];
        *(f32x4*)&cs[i][j*4] = c;
    }

    for (int mt = 0; mt < NL; mt += 16) {
        {
            f32x4 kv = *(const f32x4*)&K[((size_t)bh * NL + mt + i) * NDK + j*4];
            *(f32x4*)&ks[i][j*4] = kv;
            f32x4 pv = *(const f32x4*)&P2C[((size_t)bh * NL + mt + i) * NR + j*4];
            *(f32x4*)&ps[i][j*4] = pv;
        }
        rp[i][j] = RelPos[((size_t)b * NL + l0 + i) * NL + mt + j];
        __syncthreads();

        float s = 0.f;
        #pragma unroll
        for (int d4 = 0; d4 < 16; ++d4) {
            f32x4 qq = *(const f32x4*)&qs[i][d4*4];
            f32x4 kv = *(const f32x4*)&ks[j][d4*4];
            s += qq.x*kv.x + qq.y*kv.y + qq.z*kv.z + qq.w*kv.w;
        }
        int r = rp[i][j];
        s += cs[i][r] + ps[j][r];
        s *= (1.0f / 24.0f);   // 1 / (3 * sqrt(64))

        int mg = b * NL + mt + j;
        float mval;
        if (mlayout == 0)      mval = (float)mu[mg];
        else if (mlayout == 1) mval = ((const float*)MaskP)[mg];
        else                   mval = (float)((const int*)MaskP)[mg];
        if (mval != 0.0f) s = -1e9f;

        sc[i][mt + j] = s;
        __syncthreads();
    }

    // ---- softmax: row i handled by its 16 lanes j ----
    float mx = -INFINITY;
    #pragma unroll
    for (int s16 = 0; s16 < 16; ++s16) mx = fmaxf(mx, sc[i][j + 16*s16]);
    #pragma unroll
    for (int off = 8; off >= 1; off >>= 1) mx = fmaxf(mx, __shfl_xor(mx, off, 16));

    float sum = 0.f;
    #pragma unroll
    for (int s16 = 0; s16 < 16; ++s16) {
        float e = __expf(sc[i][j + 16*s16] - mx);
        sc[i][j + 16*s16] = e;
        sum += e;
    }
    #pragma unroll
    for (int off = 8; off >= 1; off >>= 1) sum += __shfl_xor(sum, off, 16);
    float inv = 1.0f / sum;

    #pragma unroll
    for (int s16 = 0; s16 < 16; ++s16)
        Pout[((size_t)bh * NL + l0 + i) * NL + j + 16*s16] = sc[i][j + 16*s16] * inv;
}

// ---------------------------------------------------------------------------
// Kernel 3: ctx[b,h,l,d] = sum_m p[b,h,l,m] * (v[b,h,m,d] + rel_v[b,l,m,h*64+d])
// One block per (b,l); streams the 512 KB rel_v slice (nontemporal).
// ---------------------------------------------------------------------------
__global__ __launch_bounds__(256)
void ctx_kernel(const float* __restrict__ P, const float* __restrict__ V,
                const float* __restrict__ RV, float* __restrict__ CTX)
{
    const int bl = blockIdx.x;
    const int b  = bl >> 8;
    const int l  = bl & 255;
    const int t  = threadIdx.x;

    __shared__ float pw[8][256];
    __shared__ f32x4 redv[128];

    #pragma unroll
    for (int h = 0; h < 8; ++h)
        pw[h][t] = P[(((size_t)(b*NH + h) * NL) + l) * NL + t];
    __syncthreads();

    const int c    = t & 127;    // float4-column 0..127 (head = c>>4)
    const int half = t >> 7;     // m parity
    const int hc   = c >> 4;
    const int dk4  = c & 15;

    const f32x4* rv4 = (const f32x4*)RV + (size_t)bl * NL * 128 + c;
    const f32x4* vv4 = (const f32x4*)V  + ((size_t)(b*NH + hc) * NL) * 16 + dk4;

    f32x4 acc = {0.f, 0.f, 0.f, 0.f};
    #pragma unroll 4
    for (int m = half; m < NL; m += 2) {
        float  w  = pw[hc][m];
        f32x4 rv = __builtin_nontemporal_load(rv4 + (size_t)m * 128);
        f32x4 vv = vv4[(size_t)m * 16];
        acc.x += w * (rv.x + vv.x);
        acc.y += w * (rv.y + vv.y);
        acc.z += w * (rv.z + vv.z);
        acc.w += w * (rv.w + vv.w);
    }

    if (half) redv[c] = acc;
    __syncthreads();
    if (!half) {
        f32x4 r2 = redv[c];
        acc.x += r2.x; acc.y += r2.y; acc.z += r2.z; acc.w += r2.w;
        *(f32x4*)&CTX[(size_t)bl * ND + c*4] = acc;
    }
}

// ---------------------------------------------------------------------------
// Kernel 4: out = ctx @ Wo^T + bo.  32x64 tiles, transposed LDS. 256 blocks.
// ---------------------------------------------------------------------------
__global__ __launch_bounds__(256)
void out_proj_kernel(const float* __restrict__ A, const float* __restrict__ W,
                     const float* __restrict__ bias, float* __restrict__ C)
{
    __shared__ float Ast[16][36];
    __shared__ float Bst[16][68];

    const int t  = threadIdx.x;
    const int ty = t >> 4;
    const int tx = t & 15;

    const int row0 = blockIdx.x * 32;
    const int col0 = blockIdx.y * 64;

    float acc[2][4] = {{0.f,0.f,0.f,0.f},{0.f,0.f,0.f,0.f}};

    for (int kt = 0; kt < ND; kt += 16) {
        if (t < 128) {
            int lr = t >> 2, lk = (t & 3) << 2;
            f32x4 a = *(const f32x4*)&A[(size_t)(row0 + lr) * ND + kt + lk];
            Ast[lk+0][lr] = a.x; Ast[lk+1][lr] = a.y;
            Ast[lk+2][lr] = a.z; Ast[lk+3][lr] = a.w;
        }
        {
            int lr = t >> 2, lk = (t & 3) << 2;
            f32x4 b = *(const f32x4*)&W[(size_t)(col0 + lr) * ND + kt + lk];
            Bst[lk+0][lr] = b.x; Bst[lk+1][lr] = b.y;
            Bst[lk+2][lr] = b.z; Bst[lk+3][lr] = b.w;
        }
        __syncthreads();
        #pragma unroll
        for (int kk = 0; kk < 16; ++kk) {
            float2 a2 = *(const float2*)&Ast[kk][ty*2];
            f32x4  b4 = *(const f32x4*)&Bst[kk][tx*4];
            acc[0][0] += a2.x*b4.x; acc[0][1] += a2.x*b4.y;
            acc[0][2] += a2.x*b4.z; acc[0][3] += a2.x*b4.w;
            acc[1][0] += a2.y*b4.x; acc[1][1] += a2.y*b4.y;
            acc[1][2] += a2.y*b4.z; acc[1][3] += a2.y*b4.w;
        }
        __syncthreads();
    }

    f32x4 bb = *(const f32x4*)&bias[col0 + tx*4];
    #pragma unroll
    for (int i = 0; i < 2; ++i) {
        int r = row0 + ty*2 + i;
        f32x4 o;
        o.x = acc[i][0] + bb.x; o.y = acc[i][1] + bb.y;
        o.z = acc[i][2] + bb.z; o.w = acc[i][3] + bb.w;
        *(f32x4*)&C[(size_t)r * ND + col0 + tx*4] = o;
    }
}

// ---------------------------------------------------------------------------
extern "C" void kernel_launch(void* const* d_in, const int* in_sizes, int n_in,
                              void* d_out, int out_size, void* d_ws, size_t ws_size,
                              hipStream_t stream)
{
    const float* query   = (const float*)d_in[0];
    const float* key     = (const float*)d_in[1];
    const float* value   = (const float*)d_in[2];
    const void*  mask    = d_in[3];
    const int*   rel_pos = (const int*)d_in[4];
    const float* rel_q   = (const float*)d_in[5];
    const float* rel_k   = (const float*)d_in[6];
    const float* rel_v   = (const float*)d_in[7];
    const float* Wq = (const float*)d_in[8];
    const float* bq = (const float*)d_in[9];
    const float* Wk = (const float*)d_in[10];
    const float* bk = (const float*)d_in[11];
    const float* Wv = (const float*)d_in[12];
    const float* bv = (const float*)d_in[13];
    const float* Wo = (const float*)d_in[14];
    const float* bo = (const float*)d_in[15];

    float* ws   = (float*)d_ws;
    float* q_ws = ws;                     // B*H*L*DK = 524288
    float* k_ws = q_ws + 524288;
    float* v_ws = k_ws + 524288;
    float* c2p  = v_ws + 524288;          // [B,H,L,R] = 524288
    float* p2c  = c2p + 524288;
    float* p    = p2c + 524288;           // B*H*L*L = 2097152
    float* ctx  = p + 2097152;            // B*L*D   = 524288
    float* W3   = ctx + 524288;           // 512*512
    float* W2   = W3 + 262144;
    float* b3   = W2 + 262144;            // 512
    float* b2   = b3 + 512;

    wprep_kernel<<<dim3(64, 3), 256, 0, stream>>>(
        Wq, bq, Wk, bk, rel_k, rel_q, W3, b3, W2, b2);

    gemm5_kernel<<<dim3(32, 8, 5), 256, 0, stream>>>(
        query, key, value, Wq, bq, Wk, bk, Wv, bv, W3, b3, W2, b2,
        q_ws, k_ws, v_ws, c2p, p2c);

    scores_softmax_kernel<<<dim3(16, 32), 256, 0, stream>>>(
        q_ws, k_ws, c2p, p2c, rel_pos, mask, p);

    ctx_kernel<<<dim3(1024), 256, 0, stream>>>(p, v_ws, rel_v, ctx);

    out_proj_kernel<<<dim3(32, 8), 256, 0, stream>>>(ctx, Wo, bo, (float*)d_out);
}

// Round 4
// 169.726 us; speedup vs baseline: 1.6122x; 1.2085x over previous
//
#include <hip/hip_runtime.h>
#include <hip/hip_bf16.h>
#include <math.h>

#define NB 4
#define NL 256
#define ND 512
#define NH 8
#define NR 64
#define NDK 64

typedef float f32x4 __attribute__((ext_vector_type(4)));
typedef short s16x8 __attribute__((ext_vector_type(8)));
typedef unsigned short u16;
typedef u16 u16x4 __attribute__((ext_vector_type(4)));

static __device__ __forceinline__ u16 f2bf(float f) {
    __hip_bfloat16 h = __float2bfloat16(f);   // RNE
    return __builtin_bit_cast(unsigned short, h);
}

// ---------------------------------------------------------------------------
// Kernel A: convert inputs + weights f32 -> bf16.
// jobs: 0 query, 1 key, 2 value (524288 ea); 3 Wq, 4 Wk, 5 Wv, 6 Wo (262144).
// ---------------------------------------------------------------------------
__global__ __launch_bounds__(256)
void convert_bf16_kernel(const float* __restrict__ q, const float* __restrict__ k,
                         const float* __restrict__ v, const float* __restrict__ wq,
                         const float* __restrict__ wk, const float* __restrict__ wv,
                         const float* __restrict__ wo,
                         u16* __restrict__ oq, u16* __restrict__ ok, u16* __restrict__ ov,
                         u16* __restrict__ owq, u16* __restrict__ owk,
                         u16* __restrict__ owv, u16* __restrict__ owo)
{
    const int job = blockIdx.y;
    const float* src; u16* dst; int n;
    switch (job) {
        case 0: src = q;  dst = oq;  n = 524288; break;
        case 1: src = k;  dst = ok;  n = 524288; break;
        case 2: src = v;  dst = ov;  n = 524288; break;
        case 3: src = wq; dst = owq; n = 262144; break;
        case 4: src = wk; dst = owk; n = 262144; break;
        case 5: src = wv; dst = owv; n = 262144; break;
        default: src = wo; dst = owo; n = 262144; break;
    }
    int idx = (blockIdx.x * 256 + threadIdx.x) * 4;
    if (idx >= n) return;
    f32x4 x = *(const f32x4*)&src[idx];
    u16x4 o;
    o.x = f2bf(x.x); o.y = f2bf(x.y); o.z = f2bf(x.z); o.w = f2bf(x.w);
    *(u16x4*)&dst[idx] = o;
}

// ---------------------------------------------------------------------------
// Kernel B: W-prep (f32 compute, bf16 out).
//  z=0: W3[h*64+r][e] = sum_d rel_k[h,r,d] * Wq[h*64+d][e]   (for c2p)
//  z=1: W2[h*64+r][e] = sum_d rel_q[h,r,d] * Wk[h*64+d][e]   (for p2c)
//  z=2 (blocks 0,1): b3[hr] = rel_k[h,r,:].bq_head ; b2 from rel_q,bk (f32)
// ---------------------------------------------------------------------------
__global__ __launch_bounds__(256)
void wprep_kernel(const float* __restrict__ Wq, const float* __restrict__ bq,
                  const float* __restrict__ Wk, const float* __restrict__ bk,
                  const float* __restrict__ RelK, const float* __restrict__ RelQ,
                  u16* __restrict__ W3, float* __restrict__ b3,
                  u16* __restrict__ W2, float* __restrict__ b2)
{
    const int z = blockIdx.y;
    const int t = threadIdx.x;

    if (z == 2) {
        if (blockIdx.x >= 2) return;
        const float* rel  = blockIdx.x ? RelQ : RelK;
        const float* bias = blockIdx.x ? bk : bq;
        float* out        = blockIdx.x ? b2 : b3;
        for (int hr = t; hr < 512; hr += 256) {
            int h = hr >> 6, r = hr & 63;
            float s = 0.f;
            #pragma unroll 8
            for (int d = 0; d < 64; ++d)
                s += rel[((size_t)h * NR + r) * NDK + d] * bias[h * 64 + d];
            out[hr] = s;
        }
        return;
    }

    const float* rel = z ? RelQ : RelK;   // [8][64][64]
    const float* W   = z ? Wk : Wq;       // [512][512]
    u16* Wout        = z ? W2 : W3;

    const int h  = blockIdx.x >> 3;
    const int e0 = (blockIdx.x & 7) * 64;

    __shared__ float At[64][68];   // At[d][r]
    __shared__ float Bs[64][68];   // Bs[d][e]

    const int ty = t >> 4, tx = t & 15;

    #pragma unroll
    for (int pass = 0; pass < 4; ++pass) {
        {
            int lr = t >> 2, lk = (t & 3) << 2;
            f32x4 a = *(const f32x4*)&rel[((size_t)h * NR + lr) * NDK + pass * 16 + lk];
            At[pass*16 + lk + 0][lr] = a.x; At[pass*16 + lk + 1][lr] = a.y;
            At[pass*16 + lk + 2][lr] = a.z; At[pass*16 + lk + 3][lr] = a.w;
        }
        {
            int dr = t >> 4, ec = (t & 15) << 2;
            *(f32x4*)&Bs[pass*16 + dr][ec] =
                *(const f32x4*)&W[(size_t)(h*64 + pass*16 + dr) * ND + e0 + ec];
        }
    }
    __syncthreads();

    float acc[4][4] = {{0.f,0.f,0.f,0.f},{0.f,0.f,0.f,0.f},
                       {0.f,0.f,0.f,0.f},{0.f,0.f,0.f,0.f}};
    #pragma unroll 16
    for (int kk = 0; kk < 64; ++kk) {
        f32x4 a4 = *(const f32x4*)&At[kk][ty*4];
        f32x4 b4 = *(const f32x4*)&Bs[kk][tx*4];
        #pragma unroll
        for (int i = 0; i < 4; ++i) {
            acc[i][0] += a4[i]*b4.x; acc[i][1] += a4[i]*b4.y;
            acc[i][2] += a4[i]*b4.z; acc[i][3] += a4[i]*b4.w;
        }
    }

    #pragma unroll
    for (int i = 0; i < 4; ++i) {
        u16x4 o;
        o.x = f2bf(acc[i][0]); o.y = f2bf(acc[i][1]);
        o.z = f2bf(acc[i][2]); o.w = f2bf(acc[i][3]);
        *(u16x4*)&Wout[(size_t)(h*64 + ty*4 + i) * ND + e0 + tx*4] = o;
    }
}

// ---------------------------------------------------------------------------
// Kernel C: batched projection via MFMA (no LDS).  Out = X @ W^T + bias.
//  z=0 q->bf16, z=1 k->bf16, z=2 v->f32, z=3 c2p->f32, z=4 p2c->f32.
// Block = 64 rows x 64 cols (one head); 4 waves, wave w = rows w*16..+16.
// Fragments straight from global bf16 (L1/L2-resident).
// A-frag: lane: row=m0+(lane&15), k=(lane>>4)*8+kt*32 (16B contiguous).
// B-frag: identical k-addressing on W rows -> any within-K permutation cancels.
// D layout (m89-verified): row=(lane>>4)*4+reg, col=lane&15.
// ---------------------------------------------------------------------------
__global__ __launch_bounds__(256)
void gemm5_mfma_kernel(const u16* __restrict__ xq, const u16* __restrict__ xk,
                       const u16* __restrict__ xv,
                       const u16* __restrict__ wq, const u16* __restrict__ wk,
                       const u16* __restrict__ wv, const u16* __restrict__ w3,
                       const u16* __restrict__ w2,
                       const float* __restrict__ bq, const float* __restrict__ bk,
                       const float* __restrict__ bv, const float* __restrict__ b3,
                       const float* __restrict__ b2,
                       u16* __restrict__ qbf, u16* __restrict__ kbf,
                       float* __restrict__ v_ws, float* __restrict__ c2p,
                       float* __restrict__ p2c)
{
    const int z = blockIdx.z;
    const u16* __restrict__ X = (z==0 || z==3) ? xq : ((z==1 || z==4) ? xk : xv);
    const u16* __restrict__ W = (z==0)?wq:(z==1)?wk:(z==2)?wv:(z==3)?w3:w2;
    const float* __restrict__ bias = (z==0)?bq:(z==1)?bk:(z==2)?bv:(z==3)?b3:b2;

    const int t    = threadIdx.x;
    const int wv_  = t >> 6;
    const int lane = t & 63;
    const int lr   = lane & 15;
    const int kg   = lane >> 4;

    const int m0 = blockIdx.x * 64 + wv_ * 16;
    const int h  = blockIdx.y;
    const int n0 = h * 64;

    const u16* Ap = X + (size_t)(m0 + lr) * ND + kg * 8;
    const u16* Bp = W + (size_t)(n0 + lr) * ND + kg * 8;

    f32x4 acc[4] = {{0,0,0,0},{0,0,0,0},{0,0,0,0},{0,0,0,0}};

    for (int kt = 0; kt < 16; ++kt) {
        s16x8 a = *(const s16x8*)(Ap + kt * 32);
        #pragma unroll
        for (int nt = 0; nt < 4; ++nt) {
            s16x8 b = *(const s16x8*)(Bp + (size_t)nt * 16 * ND + kt * 32);
            acc[nt] = __builtin_amdgcn_mfma_f32_16x16x32_bf16(a, b, acc[nt], 0, 0, 0);
        }
    }

    #pragma unroll
    for (int nt = 0; nt < 4; ++nt) {
        const int col = n0 + nt * 16 + lr;
        const float bb = bias[col];
        #pragma unroll
        for (int r = 0; r < 4; ++r) {
            int row = m0 + kg * 4 + r;
            int bI  = row >> 8;
            int lI  = row & 255;
            size_t oidx = (((size_t)(bI * NH + h)) * NL + lI) * 64 + nt * 16 + lr;
            float val = acc[nt][r] + bb;
            if      (z == 0) qbf[oidx]  = f2bf(val);
            else if (z == 1) kbf[oidx]  = f2bf(val);
            else if (z == 2) v_ws[oidx] = val;
            else if (z == 3) c2p[oidx]  = val;
            else             p2c[oidx]  = val;
        }
    }
}

// ---------------------------------------------------------------------------
// Kernel D: scores via MFMA + gathers + scale + mask + softmax -> p [B,H,L,L]
// Block: (16 l-rows, bh).  Phase A: QK^T MFMA (wave w owns m-stripe w*64).
// Phase B: per-16-col tile: stage p2c rows + rel_pos, gather, scale, mask.
// Phase C: row softmax (16 lanes per row), write p (f32).
// ---------------------------------------------------------------------------
__global__ __launch_bounds__(256)
void scores_mfma_kernel(const u16* __restrict__ qbf, const u16* __restrict__ kbf,
                        const float* __restrict__ C2P, const float* __restrict__ P2C,
                        const int* __restrict__ RelPos, const void* __restrict__ MaskP,
                        float* __restrict__ Pout)
{
    const int bh = blockIdx.y;
    const int b  = bh >> 3;
    const int l0 = blockIdx.x * 16;
    const int t  = threadIdx.x;
    const int wv_  = t >> 6;
    const int lane = t & 63;
    const int i  = t >> 4;
    const int j  = t & 15;

    __shared__ float sc[16][257];
    __shared__ float cs[16][68];
    __shared__ float ps[16][68];
    __shared__ int   rp[16][16];

    // ---- detect mask buffer layout (bool-u8 / f32 / i32), deterministic ----
    const unsigned char* mu = (const unsigned char*)MaskP;
    int loc1  = mu[t*4 + 1];
    int loc23 = mu[t*4 + 2] | mu[t*4 + 3];
    int any1  = __syncthreads_or(loc1);
    int any23 = __syncthreads_or(loc23);
    const int mlayout = any1 ? 0 : (any23 ? 1 : 2);  // 0=u8, 1=f32, 2=i32

    // ---- stage c2p rows for this l-tile ----
    *(f32x4*)&cs[t >> 4][(t & 15) * 4] =
        *(const f32x4*)&C2P[(((size_t)bh * NL) + l0 + (t >> 4)) * NR + (t & 15) * 4];

    // ---- Phase A: QK^T.  A rows l0..l0+15; wave's B cols wv_*64..+64 ----
    const int lr = lane & 15;
    const int kg = lane >> 4;
    const u16* Ap = qbf + ((size_t)bh * NL + l0 + lr) * 64 + kg * 8;
    s16x8 a0 = *(const s16x8*)Ap;
    s16x8 a1 = *(const s16x8*)(Ap + 32);

    f32x4 accq[4];
    #pragma unroll
    for (int c = 0; c < 4; ++c) {
        int m0 = wv_ * 64 + c * 16;
        const u16* Bp = kbf + ((size_t)bh * NL + m0 + lr) * 64 + kg * 8;
        s16x8 b0 = *(const s16x8*)Bp;
        s16x8 b1 = *(const s16x8*)(Bp + 32);
        f32x4 acc = {0.f, 0.f, 0.f, 0.f};
        acc = __builtin_amdgcn_mfma_f32_16x16x32_bf16(a0, b0, acc, 0, 0, 0);
        acc = __builtin_amdgcn_mfma_f32_16x16x32_bf16(a1, b1, acc, 0, 0, 0);
        accq[c] = acc;
    }
    #pragma unroll
    for (int c = 0; c < 4; ++c)
        #pragma unroll
        for (int r = 0; r < 4; ++r)
            sc[kg * 4 + r][wv_ * 64 + c * 16 + lr] = accq[c][r];
    __syncthreads();

    // ---- Phase B: gathers + scale + mask, 16 cols per iteration ----
    for (int mt = 0; mt < 16; ++mt) {
        *(f32x4*)&ps[t >> 4][(t & 15) * 4] =
            *(const f32x4*)&P2C[(((size_t)bh * NL) + mt * 16 + (t >> 4)) * NR + (t & 15) * 4];
        rp[i][j] = RelPos[((size_t)b * NL + l0 + i) * NL + mt * 16 + j];
        __syncthreads();

        int r = rp[i][j];
        float s = sc[i][mt * 16 + j] + cs[i][r] + ps[j][r];
        s *= (1.0f / 24.0f);   // 1 / (3 * sqrt(64))

        int mg = b * NL + mt * 16 + j;
        float mval;
        if (mlayout == 0)      mval = (float)mu[mg];
        else if (mlayout == 1) mval = ((const float*)MaskP)[mg];
        else                   mval = (float)((const int*)MaskP)[mg];
        if (mval != 0.0f) s = -1e9f;

        sc[i][mt * 16 + j] = s;
        __syncthreads();
    }

    // ---- Phase C: softmax, row i handled by its 16 lanes j ----
    float mx = -INFINITY;
    #pragma unroll
    for (int s16 = 0; s16 < 16; ++s16) mx = fmaxf(mx, sc[i][j + 16*s16]);
    #pragma unroll
    for (int off = 8; off >= 1; off >>= 1) mx = fmaxf(mx, __shfl_xor(mx, off, 16));

    float sum = 0.f;
    #pragma unroll
    for (int s16 = 0; s16 < 16; ++s16) {
        float e = __expf(sc[i][j + 16*s16] - mx);
        sc[i][j + 16*s16] = e;
        sum += e;
    }
    #pragma unroll
    for (int off = 8; off >= 1; off >>= 1) sum += __shfl_xor(sum, off, 16);
    float inv = 1.0f / sum;

    #pragma unroll
    for (int s16 = 0; s16 < 16; ++s16)
        Pout[((size_t)bh * NL + l0 + i) * NL + j + 16*s16] = sc[i][j + 16*s16] * inv;
}

// ---------------------------------------------------------------------------
// Kernel E: ctx[b,h,l,d] = sum_m p[b,h,l,m] * (v[b,h,m,d] + rel_v[b,l,m,h*64+d])
// One block per (b,l); streams the 512 KB rel_v slice (nontemporal).
// Emits ctx as bf16 for the MFMA out-projection.
// ---------------------------------------------------------------------------
__global__ __launch_bounds__(256)
void ctx_kernel(const float* __restrict__ P, const float* __restrict__ V,
                const float* __restrict__ RV, u16* __restrict__ CTXB)
{
    const int bl = blockIdx.x;
    const int b  = bl >> 8;
    const int l  = bl & 255;
    const int t  = threadIdx.x;

    __shared__ float pw[8][256];
    __shared__ f32x4 redv[128];

    #pragma unroll
    for (int h = 0; h < 8; ++h)
        pw[h][t] = P[(((size_t)(b*NH + h) * NL) + l) * NL + t];
    __syncthreads();

    const int c    = t & 127;    // float4-column 0..127 (head = c>>4)
    const int half = t >> 7;     // m parity
    const int hc   = c >> 4;
    const int dk4  = c & 15;

    const f32x4* rv4 = (const f32x4*)RV + (size_t)bl * NL * 128 + c;
    const f32x4* vv4 = (const f32x4*)V  + ((size_t)(b*NH + hc) * NL) * 16 + dk4;

    f32x4 acc = {0.f, 0.f, 0.f, 0.f};
    #pragma unroll 4
    for (int m = half; m < NL; m += 2) {
        float  w  = pw[hc][m];
        f32x4 rv = __builtin_nontemporal_load(rv4 + (size_t)m * 128);
        f32x4 vv = vv4[(size_t)m * 16];
        acc.x += w * (rv.x + vv.x);
        acc.y += w * (rv.y + vv.y);
        acc.z += w * (rv.z + vv.z);
        acc.w += w * (rv.w + vv.w);
    }

    if (half) redv[c] = acc;
    __syncthreads();
    if (!half) {
        f32x4 r2 = redv[c];
        acc.x += r2.x; acc.y += r2.y; acc.z += r2.z; acc.w += r2.w;
        u16x4 o;
        o.x = f2bf(acc.x); o.y = f2bf(acc.y); o.z = f2bf(acc.z); o.w = f2bf(acc.w);
        *(u16x4*)&CTXB[(size_t)bl * ND + c*4] = o;
    }
}

// ---------------------------------------------------------------------------
// Kernel F: out = ctx @ Wo^T + bo via MFMA.  64x64 tiles, grid (16,8).
// ---------------------------------------------------------------------------
__global__ __launch_bounds__(256)
void out_proj_mfma_kernel(const u16* __restrict__ A, const u16* __restrict__ W,
                          const float* __restrict__ bias, float* __restrict__ C)
{
    const int t    = threadIdx.x;
    const int wv_  = t >> 6;
    const int lane = t & 63;
    const int lr   = lane & 15;
    const int kg   = lane >> 4;

    const int m0 = blockIdx.x * 64 + wv_ * 16;
    const int n0 = blockIdx.y * 64;

    const u16* Ap = A + (size_t)(m0 + lr) * ND + kg * 8;
    const u16* Bp = W + (size_t)(n0 + lr) * ND + kg * 8;

    f32x4 acc[4] = {{0,0,0,0},{0,0,0,0},{0,0,0,0},{0,0,0,0}};

    for (int kt = 0; kt < 16; ++kt) {
        s16x8 a = *(const s16x8*)(Ap + kt * 32);
        #pragma unroll
        for (int nt = 0; nt < 4; ++nt) {
            s16x8 b = *(const s16x8*)(Bp + (size_t)nt * 16 * ND + kt * 32);
            acc[nt] = __builtin_amdgcn_mfma_f32_16x16x32_bf16(a, b, acc[nt], 0, 0, 0);
        }
    }

    #pragma unroll
    for (int nt = 0; nt < 4; ++nt) {
        const int col = n0 + nt * 16 + lr;
        const float bb = bias[col];
        #pragma unroll
        for (int r = 0; r < 4; ++r) {
            int row = m0 + kg * 4 + r;
            C[(size_t)row * ND + col] = acc[nt][r] + bb;
        }
    }
}

// ---------------------------------------------------------------------------
extern "C" void kernel_launch(void* const* d_in, const int* in_sizes, int n_in,
                              void* d_out, int out_size, void* d_ws, size_t ws_size,
                              hipStream_t stream)
{
    const float* query   = (const float*)d_in[0];
    const float* key     = (const float*)d_in[1];
    const float* value   = (const float*)d_in[2];
    const void*  mask    = d_in[3];
    const int*   rel_pos = (const int*)d_in[4];
    const float* rel_q   = (const float*)d_in[5];
    const float* rel_k   = (const float*)d_in[6];
    const float* rel_v   = (const float*)d_in[7];
    const float* Wq = (const float*)d_in[8];
    const float* bq = (const float*)d_in[9];
    const float* Wk = (const float*)d_in[10];
    const float* bk = (const float*)d_in[11];
    const float* Wv = (const float*)d_in[12];
    const float* bv = (const float*)d_in[13];
    const float* Wo = (const float*)d_in[14];
    const float* bo = (const float*)d_in[15];

    // ---- workspace layout ----
    float* wsf  = (float*)d_ws;
    float* v_ws = wsf;                    // 524288 f32
    float* c2p  = v_ws + 524288;          // 524288 f32
    float* p2c  = c2p + 524288;           // 524288 f32
    float* p    = p2c + 524288;           // 2097152 f32
    float* b3   = p + 2097152;            // 512 f32
    float* b2   = b3 + 512;               // 512 f32
    u16* wsu  = (u16*)(b2 + 512);
    u16* xqb  = wsu;                      // 524288 u16
    u16* xkb  = xqb + 524288;
    u16* xvb  = xkb + 524288;
    u16* wqb  = xvb + 524288;             // 262144 u16
    u16* wkb  = wqb + 262144;
    u16* wvb  = wkb + 262144;
    u16* wob  = wvb + 262144;
    u16* w3b  = wob + 262144;
    u16* w2b  = w3b + 262144;
    u16* qbf  = w2b + 262144;             // 524288 u16
    u16* kbf  = qbf + 524288;
    u16* ctxb = kbf + 524288;             // 524288 u16

    convert_bf16_kernel<<<dim3(512, 7), 256, 0, stream>>>(
        query, key, value, Wq, Wk, Wv, Wo, xqb, xkb, xvb, wqb, wkb, wvb, wob);

    wprep_kernel<<<dim3(64, 3), 256, 0, stream>>>(
        Wq, bq, Wk, bk, rel_k, rel_q, w3b, b3, w2b, b2);

    gemm5_mfma_kernel<<<dim3(16, 8, 5), 256, 0, stream>>>(
        xqb, xkb, xvb, wqb, wkb, wvb, w3b, w2b,
        bq, bk, bv, b3, b2, qbf, kbf, v_ws, c2p, p2c);

    scores_mfma_kernel<<<dim3(16, 32), 256, 0, stream>>>(
        qbf, kbf, c2p, p2c, rel_pos, mask, p);

    ctx_kernel<<<dim3(1024), 256, 0, stream>>>(p, v_ws, rel_v, ctxb);

    out_proj_mfma_kernel<<<dim3(16, 8), 256, 0, stream>>>(ctxb, wob, bo, (float*)d_out);
}

// Round 5
// 169.232 us; speedup vs baseline: 1.6169x; 1.0029x over previous
//
#include <hip/hip_runtime.h>
#include <hip/hip_bf16.h>
#include <math.h>

#define NB 4
#define NL 256
#define ND 512
#define NH 8
#define NR 64
#define NDK 64

typedef float f32x4 __attribute__((ext_vector_type(4)));
typedef short s16x8 __attribute__((ext_vector_type(8)));
typedef unsigned short u16;
typedef u16 u16x4 __attribute__((ext_vector_type(4)));

static __device__ __forceinline__ u16 f2bf(float f) {
    __hip_bfloat16 h = __float2bfloat16(f);   // RNE
    return __builtin_bit_cast(unsigned short, h);
}

// ---------------------------------------------------------------------------
// Kernel A: convert inputs + weights f32 -> bf16.
// jobs: 0 query, 1 key, 2 value (524288 ea); 3 Wq, 4 Wk, 5 Wv, 6 Wo (262144).
// ---------------------------------------------------------------------------
__global__ __launch_bounds__(256)
void convert_bf16_kernel(const float* __restrict__ q, const float* __restrict__ k,
                         const float* __restrict__ v, const float* __restrict__ wq,
                         const float* __restrict__ wk, const float* __restrict__ wv,
                         const float* __restrict__ wo,
                         u16* __restrict__ oq, u16* __restrict__ ok, u16* __restrict__ ov,
                         u16* __restrict__ owq, u16* __restrict__ owk,
                         u16* __restrict__ owv, u16* __restrict__ owo)
{
    const int job = blockIdx.y;
    const float* src; u16* dst; int n;
    switch (job) {
        case 0: src = q;  dst = oq;  n = 524288; break;
        case 1: src = k;  dst = ok;  n = 524288; break;
        case 2: src = v;  dst = ov;  n = 524288; break;
        case 3: src = wq; dst = owq; n = 262144; break;
        case 4: src = wk; dst = owk; n = 262144; break;
        case 5: src = wv; dst = owv; n = 262144; break;
        default: src = wo; dst = owo; n = 262144; break;
    }
    int idx = (blockIdx.x * 256 + threadIdx.x) * 4;
    if (idx >= n) return;
    f32x4 x = *(const f32x4*)&src[idx];
    u16x4 o;
    o.x = f2bf(x.x); o.y = f2bf(x.y); o.z = f2bf(x.z); o.w = f2bf(x.w);
    *(u16x4*)&dst[idx] = o;
}

// ---------------------------------------------------------------------------
// Kernel B: W-prep (f32 compute, bf16 out).
//  z=0: W3[h*64+r][e] = sum_d rel_k[h,r,d] * Wq[h*64+d][e]   (for c2p)
//  z=1: W2[h*64+r][e] = sum_d rel_q[h,r,d] * Wk[h*64+d][e]   (for p2c)
//  z=2 (blocks 0,1): b3[hr] = rel_k[h,r,:].bq_head ; b2 from rel_q,bk (f32)
// ---------------------------------------------------------------------------
__global__ __launch_bounds__(256)
void wprep_kernel(const float* __restrict__ Wq, const float* __restrict__ bq,
                  const float* __restrict__ Wk, const float* __restrict__ bk,
                  const float* __restrict__ RelK, const float* __restrict__ RelQ,
                  u16* __restrict__ W3, float* __restrict__ b3,
                  u16* __restrict__ W2, float* __restrict__ b2)
{
    const int z = blockIdx.y;
    const int t = threadIdx.x;

    if (z == 2) {
        if (blockIdx.x >= 2) return;
        const float* rel  = blockIdx.x ? RelQ : RelK;
        const float* bias = blockIdx.x ? bk : bq;
        float* out        = blockIdx.x ? b2 : b3;
        for (int hr = t; hr < 512; hr += 256) {
            int h = hr >> 6, r = hr & 63;
            float s = 0.f;
            #pragma unroll 8
            for (int d = 0; d < 64; ++d)
                s += rel[((size_t)h * NR + r) * NDK + d] * bias[h * 64 + d];
            out[hr] = s;
        }
        return;
    }

    const float* rel = z ? RelQ : RelK;   // [8][64][64]
    const float* W   = z ? Wk : Wq;       // [512][512]
    u16* Wout        = z ? W2 : W3;

    const int h  = blockIdx.x >> 3;
    const int e0 = (blockIdx.x & 7) * 64;

    __shared__ float At[64][68];   // At[d][r]
    __shared__ float Bs[64][68];   // Bs[d][e]

    const int ty = t >> 4, tx = t & 15;

    #pragma unroll
    for (int pass = 0; pass < 4; ++pass) {
        {
            int lr = t >> 2, lk = (t & 3) << 2;
            f32x4 a = *(const f32x4*)&rel[((size_t)h * NR + lr) * NDK + pass * 16 + lk];
            At[pass*16 + lk + 0][lr] = a.x; At[pass*16 + lk + 1][lr] = a.y;
            At[pass*16 + lk + 2][lr] = a.z; At[pass*16 + lk + 3][lr] = a.w;
        }
        {
            int dr = t >> 4, ec = (t & 15) << 2;
            *(f32x4*)&Bs[pass*16 + dr][ec] =
                *(const f32x4*)&W[(size_t)(h*64 + pass*16 + dr) * ND + e0 + ec];
        }
    }
    __syncthreads();

    float acc[4][4] = {{0.f,0.f,0.f,0.f},{0.f,0.f,0.f,0.f},
                       {0.f,0.f,0.f,0.f},{0.f,0.f,0.f,0.f}};
    #pragma unroll 16
    for (int kk = 0; kk < 64; ++kk) {
        f32x4 a4 = *(const f32x4*)&At[kk][ty*4];
        f32x4 b4 = *(const f32x4*)&Bs[kk][tx*4];
        #pragma unroll
        for (int i = 0; i < 4; ++i) {
            acc[i][0] += a4[i]*b4.x; acc[i][1] += a4[i]*b4.y;
            acc[i][2] += a4[i]*b4.z; acc[i][3] += a4[i]*b4.w;
        }
    }

    #pragma unroll
    for (int i = 0; i < 4; ++i) {
        u16x4 o;
        o.x = f2bf(acc[i][0]); o.y = f2bf(acc[i][1]);
        o.z = f2bf(acc[i][2]); o.w = f2bf(acc[i][3]);
        *(u16x4*)&Wout[(size_t)(h*64 + ty*4 + i) * ND + e0 + tx*4] = o;
    }
}

// ---------------------------------------------------------------------------
// Kernel C: batched projection via MFMA (no LDS).  Out = X @ W^T + bias.
//  z=0 q->bf16, z=1 k->bf16, z=2 v->f32, z=3 c2p->f32, z=4 p2c->f32.
// Block = 64 rows x 64 cols (one head); 4 waves, wave w = rows w*16..+16.
// ---------------------------------------------------------------------------
__global__ __launch_bounds__(256)
void gemm5_mfma_kernel(const u16* __restrict__ xq, const u16* __restrict__ xk,
                       const u16* __restrict__ xv,
                       const u16* __restrict__ wq, const u16* __restrict__ wk,
                       const u16* __restrict__ wv, const u16* __restrict__ w3,
                       const u16* __restrict__ w2,
                       const float* __restrict__ bq, const float* __restrict__ bk,
                       const float* __restrict__ bv, const float* __restrict__ b3,
                       const float* __restrict__ b2,
                       u16* __restrict__ qbf, u16* __restrict__ kbf,
                       float* __restrict__ v_ws, float* __restrict__ c2p,
                       float* __restrict__ p2c)
{
    const int z = blockIdx.z;
    const u16* __restrict__ X = (z==0 || z==3) ? xq : ((z==1 || z==4) ? xk : xv);
    const u16* __restrict__ W = (z==0)?wq:(z==1)?wk:(z==2)?wv:(z==3)?w3:w2;
    const float* __restrict__ bias = (z==0)?bq:(z==1)?bk:(z==2)?bv:(z==3)?b3:b2;

    const int t    = threadIdx.x;
    const int wv_  = t >> 6;
    const int lane = t & 63;
    const int lr   = lane & 15;
    const int kg   = lane >> 4;

    const int m0 = blockIdx.x * 64 + wv_ * 16;
    const int h  = blockIdx.y;
    const int n0 = h * 64;

    const u16* Ap = X + (size_t)(m0 + lr) * ND + kg * 8;
    const u16* Bp = W + (size_t)(n0 + lr) * ND + kg * 8;

    f32x4 acc[4] = {{0,0,0,0},{0,0,0,0},{0,0,0,0},{0,0,0,0}};

    for (int kt = 0; kt < 16; ++kt) {
        s16x8 a = *(const s16x8*)(Ap + kt * 32);
        #pragma unroll
        for (int nt = 0; nt < 4; ++nt) {
            s16x8 b = *(const s16x8*)(Bp + (size_t)nt * 16 * ND + kt * 32);
            acc[nt] = __builtin_amdgcn_mfma_f32_16x16x32_bf16(a, b, acc[nt], 0, 0, 0);
        }
    }

    #pragma unroll
    for (int nt = 0; nt < 4; ++nt) {
        const int col = n0 + nt * 16 + lr;
        const float bb = bias[col];
        #pragma unroll
        for (int r = 0; r < 4; ++r) {
            int row = m0 + kg * 4 + r;
            int bI  = row >> 8;
            int lI  = row & 255;
            size_t oidx = (((size_t)(bI * NH + h)) * NL + lI) * 64 + nt * 16 + lr;
            float val = acc[nt][r] + bb;
            if      (z == 0) qbf[oidx]  = f2bf(val);
            else if (z == 1) kbf[oidx]  = f2bf(val);
            else if (z == 2) v_ws[oidx] = val;
            else if (z == 3) c2p[oidx]  = val;
            else             p2c[oidx]  = val;
        }
    }
}

// ---------------------------------------------------------------------------
// Kernel D (FUSED): scores (MFMA) + gathers + softmax + ctx stream.
// Block = (16 l-rows, bh), 512 threads (8 waves), grid (16,32)=512 = 2/CU.
//  A: QK^T MFMA, wave w owns m-stripe w*32.
//  B: 8 iters x 32 cols: stage p2c tile, gather c2p/p2c via rel_pos, mask.
//  C: softmax (32 lanes per row), p left in LDS (f32).
//  D: stream rel_v[b, l0+i, m, h*64+64) (nontemporal, read-once) fused with
//     p @ V; ctx written bf16 [B*L, 512].
// ---------------------------------------------------------------------------
__global__ __launch_bounds__(512, 4)
void attn_ctx_kernel(const u16* __restrict__ qbf, const u16* __restrict__ kbf,
                     const float* __restrict__ Vws,
                     const float* __restrict__ C2P, const float* __restrict__ P2C,
                     const int* __restrict__ RelPos, const void* __restrict__ MaskP,
                     const float* __restrict__ RV, u16* __restrict__ CTXB)
{
    const int bh = blockIdx.y;
    const int b  = bh >> 3;
    const int h  = bh & 7;
    const int l0 = blockIdx.x * 16;
    const int t  = threadIdx.x;

    __shared__ float sc[16][257];   // scores -> p   (16.4 KB)
    __shared__ float cs[16][64];    // c2p rows      (4 KB)
    __shared__ float ps[32][68];    // p2c staging   (8.7 KB)
    __shared__ f32x4 redv[256];     // phase-D cross-half reduce (4 KB)

    // ---- detect mask buffer layout (bool-u8 / f32 / i32), deterministic ----
    const unsigned char* mu = (const unsigned char*)MaskP;
    int loc1 = 0, loc23 = 0;
    if (t < 250) {                       // sample first 1000 bytes only
        loc1  = mu[t*4 + 1];
        loc23 = mu[t*4 + 2] | mu[t*4 + 3];
    }
    int any1  = __syncthreads_or(loc1);
    int any23 = __syncthreads_or(loc23);
    const int mlayout = any1 ? 0 : (any23 ? 1 : 2);  // 0=u8, 1=f32, 2=i32

    // ---- stage c2p rows for this l-tile (first 256 threads) ----
    if (t < 256)
        *(f32x4*)&cs[t >> 4][(t & 15) * 4] =
            *(const f32x4*)&C2P[(((size_t)bh * NL) + l0 + (t >> 4)) * NR + (t & 15) * 4];

    // ---- Phase A: QK^T MFMA.  wave wv: m-stripe wv*32, two 16-col tiles ----
    {
        const int wv_  = t >> 6;
        const int lane = t & 63;
        const int lr   = lane & 15;
        const int kg   = lane >> 4;
        const u16* Ap = qbf + ((size_t)bh * NL + l0 + lr) * 64 + kg * 8;
        s16x8 a0 = *(const s16x8*)Ap;
        s16x8 a1 = *(const s16x8*)(Ap + 32);
        #pragma unroll
        for (int c = 0; c < 2; ++c) {
            int m0 = wv_ * 32 + c * 16;
            const u16* Bp = kbf + ((size_t)bh * NL + m0 + lr) * 64 + kg * 8;
            s16x8 b0 = *(const s16x8*)Bp;
            s16x8 b1 = *(const s16x8*)(Bp + 32);
            f32x4 acc = {0.f, 0.f, 0.f, 0.f};
            acc = __builtin_amdgcn_mfma_f32_16x16x32_bf16(a0, b0, acc, 0, 0, 0);
            acc = __builtin_amdgcn_mfma_f32_16x16x32_bf16(a1, b1, acc, 0, 0, 0);
            #pragma unroll
            for (int r = 0; r < 4; ++r)
                sc[kg * 4 + r][m0 + lr] = acc[r];
        }
    }
    __syncthreads();

    // ---- Phase B: gathers + scale + mask, 32 cols per iteration ----
    const int i  = t >> 5;        // row 0..15
    const int jj = t & 31;        // col lane 0..31
    for (int mt = 0; mt < 8; ++mt) {
        // stage p2c rows mt*32 .. +32 (512 threads: row=t>>4, col4=t&15)
        *(f32x4*)&ps[t >> 4][(t & 15) * 4] =
            *(const f32x4*)&P2C[(((size_t)bh * NL) + mt * 32 + (t >> 4)) * NR + (t & 15) * 4];
        __syncthreads();

        const int m = mt * 32 + jj;
        int r = RelPos[((size_t)b * NL + l0 + i) * NL + m];
        float s = sc[i][m] + cs[i][r] + ps[jj][r];
        s *= (1.0f / 24.0f);   // 1 / (3 * sqrt(64))

        float mval;
        if (mlayout == 0)      mval = (float)mu[b * NL + m];
        else if (mlayout == 1) mval = ((const float*)MaskP)[b * NL + m];
        else                   mval = (float)((const int*)MaskP)[b * NL + m];
        if (mval != 0.0f) s = -1e9f;

        __syncthreads();
        sc[i][m] = s;
        __syncthreads();
    }

    // ---- Phase C: softmax, row i handled by its 32 lanes jj ----
    {
        float mx = -INFINITY;
        #pragma unroll
        for (int s32 = 0; s32 < 8; ++s32) mx = fmaxf(mx, sc[i][jj + 32*s32]);
        #pragma unroll
        for (int off = 16; off >= 1; off >>= 1) mx = fmaxf(mx, __shfl_xor(mx, off, 32));

        float sum = 0.f;
        float ev[8];
        #pragma unroll
        for (int s32 = 0; s32 < 8; ++s32) {
            ev[s32] = __expf(sc[i][jj + 32*s32] - mx);
            sum += ev[s32];
        }
        #pragma unroll
        for (int off = 16; off >= 1; off >>= 1) sum += __shfl_xor(sum, off, 32);
        float inv = 1.0f / sum;
        #pragma unroll
        for (int s32 = 0; s32 < 8; ++s32) sc[i][jj + 32*s32] = ev[s32] * inv;
    }
    __syncthreads();

    // ---- Phase D: ctx[i][d] = sum_m p[i][m] * (v[m][d] + rel_v[l0+i][m][d]) ----
    {
        const int half = t >> 8;        // m parity
        const int di   = (t >> 4) & 15; // row 0..15
        const int d4   = t & 15;        // f32x4 column 0..15

        const float* rvp = RV + (((size_t)(b * NL + l0 + di)) * NL) * ND + h * 64 + d4 * 4;
        const float* vvp = Vws + ((size_t)(b * NH + h) * NL) * 64 + d4 * 4;

        f32x4 acc = {0.f, 0.f, 0.f, 0.f};
        #pragma unroll 4
        for (int m = half; m < NL; m += 2) {
            float w  = sc[di][m];
            f32x4 rv = __builtin_nontemporal_load((const f32x4*)(rvp + (size_t)m * ND));
            f32x4 vv = *(const f32x4*)(vvp + (size_t)m * 64);
            acc += w * (rv + vv);
        }

        if (half) redv[t & 255] = acc;
        __syncthreads();
        if (!half) {
            acc += redv[t];
            u16x4 o;
            o.x = f2bf(acc.x); o.y = f2bf(acc.y); o.z = f2bf(acc.z); o.w = f2bf(acc.w);
            *(u16x4*)&CTXB[((size_t)(b * NL + l0 + di)) * ND + h * 64 + d4 * 4] = o;
        }
    }
}

// ---------------------------------------------------------------------------
// Kernel E: out = ctx @ Wo^T + bo via MFMA.  32x64 tiles, grid (32,8)=256.
// wave w: rows (w&1)*16, cols (w>>1)*32.
// ---------------------------------------------------------------------------
__global__ __launch_bounds__(256)
void out_proj_mfma_kernel(const u16* __restrict__ A, const u16* __restrict__ W,
                          const float* __restrict__ bias, float* __restrict__ C)
{
    const int t    = threadIdx.x;
    const int wv_  = t >> 6;
    const int lane = t & 63;
    const int lr   = lane & 15;
    const int kg   = lane >> 4;

    const int m0 = blockIdx.x * 32 + (wv_ & 1) * 16;
    const int n0 = blockIdx.y * 64 + (wv_ >> 1) * 32;

    const u16* Ap = A + (size_t)(m0 + lr) * ND + kg * 8;
    const u16* Bp = W + (size_t)(n0 + lr) * ND + kg * 8;

    f32x4 acc[2] = {{0,0,0,0},{0,0,0,0}};

    for (int kt = 0; kt < 16; ++kt) {
        s16x8 a = *(const s16x8*)(Ap + kt * 32);
        #pragma unroll
        for (int nt = 0; nt < 2; ++nt) {
            s16x8 b = *(const s16x8*)(Bp + (size_t)nt * 16 * ND + kt * 32);
            acc[nt] = __builtin_amdgcn_mfma_f32_16x16x32_bf16(a, b, acc[nt], 0, 0, 0);
        }
    }

    #pragma unroll
    for (int nt = 0; nt < 2; ++nt) {
        const int col = n0 + nt * 16 + lr;
        const float bb = bias[col];
        #pragma unroll
        for (int r = 0; r < 4; ++r) {
            int row = m0 + kg * 4 + r;
            C[(size_t)row * ND + col] = acc[nt][r] + bb;
        }
    }
}

// ---------------------------------------------------------------------------
extern "C" void kernel_launch(void* const* d_in, const int* in_sizes, int n_in,
                              void* d_out, int out_size, void* d_ws, size_t ws_size,
                              hipStream_t stream)
{
    const float* query   = (const float*)d_in[0];
    const float* key     = (const float*)d_in[1];
    const float* value   = (const float*)d_in[2];
    const void*  mask    = d_in[3];
    const int*   rel_pos = (const int*)d_in[4];
    const float* rel_q   = (const float*)d_in[5];
    const float* rel_k   = (const float*)d_in[6];
    const float* rel_v   = (const float*)d_in[7];
    const float* Wq = (const float*)d_in[8];
    const float* bq = (const float*)d_in[9];
    const float* Wk = (const float*)d_in[10];
    const float* bk = (const float*)d_in[11];
    const float* Wv = (const float*)d_in[12];
    const float* bv = (const float*)d_in[13];
    const float* Wo = (const float*)d_in[14];
    const float* bo = (const float*)d_in[15];

    // ---- workspace layout ----
    float* wsf  = (float*)d_ws;
    float* v_ws = wsf;                    // 524288 f32
    float* c2p  = v_ws + 524288;          // 524288 f32
    float* p2c  = c2p + 524288;           // 524288 f32
    float* b3   = p2c + 524288;           // 512 f32
    float* b2   = b3 + 512;               // 512 f32
    u16* wsu  = (u16*)(b2 + 512);
    u16* xqb  = wsu;                      // 524288 u16
    u16* xkb  = xqb + 524288;
    u16* xvb  = xkb + 524288;
    u16* wqb  = xvb + 524288;             // 262144 u16
    u16* wkb  = wqb + 262144;
    u16* wvb  = wkb + 262144;
    u16* wob  = wvb + 262144;
    u16* w3b  = wob + 262144;
    u16* w2b  = w3b + 262144;
    u16* qbf  = w2b + 262144;             // 524288 u16
    u16* kbf  = qbf + 524288;
    u16* ctxb = kbf + 524288;             // 524288 u16

    convert_bf16_kernel<<<dim3(512, 7), 256, 0, stream>>>(
        query, key, value, Wq, Wk, Wv, Wo, xqb, xkb, xvb, wqb, wkb, wvb, wob);

    wprep_kernel<<<dim3(64, 3), 256, 0, stream>>>(
        Wq, bq, Wk, bk, rel_k, rel_q, w3b, b3, w2b, b2);

    gemm5_mfma_kernel<<<dim3(16, 8, 5), 256, 0, stream>>>(
        xqb, xkb, xvb, wqb, wkb, wvb, w3b, w2b,
        bq, bk, bv, b3, b2, qbf, kbf, v_ws, c2p, p2c);

    attn_ctx_kernel<<<dim3(16, 32), 512, 0, stream>>>(
        qbf, kbf, v_ws, c2p, p2c, rel_pos, mask, rel_v, ctxb);

    out_proj_mfma_kernel<<<dim3(32, 8), 256, 0, stream>>>(ctxb, wob, bo, (float*)d_out);
}